// Round 4
// baseline (660.332 us; speedup 1.0000x reference)
//
#include <hip/hip_runtime.h>

// ---------------------------------------------------------------------------
// GNN: 3x GraphConv(H=64) + global_mean_pool + Linear(64->2)
// N=100000, E=1200000, G=256, C_IN=1, C_OUT=2
//
// Round-4: k_node2 -> quad-per-node (4 threads/node, 32 k-values each in
// registers), weights streamed from L1 (8KB hot set), shfl_xor combine.
// 128 FMA wave-instrs per node is the floor; this runs at ~68% FMA density
// with 4x the wave count of round-3's thread-per-node version.
// ---------------------------------------------------------------------------

static __device__ __forceinline__ float4 ld4(const float* p) {
    return *reinterpret_cast<const float4*>(p);
}

// Precompute:
//  Wc[j][0..127]  = { W2_rel[k][j] k=0..63 , W2_root[k][j] k=0..63 }  (32 KB)
//  MCf[j*4+p]     = { Mrel[j][0], Mrel[j][1], Mroot[j][0], Mroot[j][1] }[p]
//  b3W[c]         = b3 @ W_lin
__global__ void k_small(const float* __restrict__ W3_rel, const float* __restrict__ b3,
                        const float* __restrict__ W3_root, const float* __restrict__ W_lin,
                        const float* __restrict__ W2_rel, const float* __restrict__ W2_root,
                        float4* __restrict__ MC4, float* __restrict__ b3W,
                        float* __restrict__ Wc)
{
    int t = threadIdx.x;
    for (int i = t; i < 8192; i += 256) {
        int j = i >> 7, r = i & 127;
        Wc[i] = (r < 64) ? W2_rel[r * 64 + j] : W2_root[(r - 64) * 64 + j];
    }
    if (t < 64) {
        float sr0 = 0.f, sr1 = 0.f, so0 = 0.f, so1 = 0.f;
        for (int k = 0; k < 64; ++k) {
            float wl0 = W_lin[k * 2 + 0], wl1 = W_lin[k * 2 + 1];
            sr0 += W3_rel[t * 64 + k] * wl0;
            sr1 += W3_rel[t * 64 + k] * wl1;
            so0 += W3_root[t * 64 + k] * wl0;
            so1 += W3_root[t * 64 + k] * wl1;
        }
        MC4[t] = make_float4(sr0, sr1, so0, so1);
    }
    if (t < 2) {
        float s = 0.f;
        for (int k = 0; k < 64; ++k) s += b3[k] * W_lin[k * 2 + t];
        b3W[t] = s;
    }
}

// ---- CSR build -------------------------------------------------------------
__global__ __launch_bounds__(256) void k_hist(const int* __restrict__ dst,
                                              int* __restrict__ deg, int E)
{
    int e = blockIdx.x * 256 + threadIdx.x;
    if (e < E) atomicAdd(&deg[dst[e]], 1);
}

__global__ __launch_bounds__(256) void k_blocksum(const int* __restrict__ deg,
                                                  int* __restrict__ bsum, int N)
{
    __shared__ int s[256];
    int i = blockIdx.x * 256 + threadIdx.x;
    s[threadIdx.x] = (i < N) ? deg[i] : 0;
    __syncthreads();
    for (int o = 128; o > 0; o >>= 1) {
        if (threadIdx.x < o) s[threadIdx.x] += s[threadIdx.x + o];
        __syncthreads();
    }
    if (threadIdx.x == 0) bsum[blockIdx.x] = s[0];
}

__global__ __launch_bounds__(256) void k_scanbsum(const int* __restrict__ bsum,
                                                  int* __restrict__ bpref, int nb)
{
    __shared__ int s[256];
    __shared__ int carry;
    if (threadIdx.x == 0) carry = 0;
    __syncthreads();
    for (int base = 0; base < nb; base += 256) {
        int i = base + threadIdx.x;
        int v = (i < nb) ? bsum[i] : 0;
        s[threadIdx.x] = v;
        __syncthreads();
        for (int off = 1; off < 256; off <<= 1) {
            int t = (threadIdx.x >= off) ? s[threadIdx.x - off] : 0;
            __syncthreads();
            s[threadIdx.x] += t;
            __syncthreads();
        }
        if (i < nb) bpref[i] = carry + s[threadIdx.x] - v;  // exclusive
        __syncthreads();
        if (threadIdx.x == 0) carry += s[255];
        __syncthreads();
    }
}

__global__ __launch_bounds__(256) void k_scan3(const int* __restrict__ deg,
                                               const int* __restrict__ bpref,
                                               int* __restrict__ rowptr, int N, int E)
{
    __shared__ int s[256];
    int i = blockIdx.x * 256 + threadIdx.x;
    int v = (i < N) ? deg[i] : 0;
    s[threadIdx.x] = v;
    __syncthreads();
    for (int off = 1; off < 256; off <<= 1) {
        int t = (threadIdx.x >= off) ? s[threadIdx.x - off] : 0;
        __syncthreads();
        s[threadIdx.x] += t;
        __syncthreads();
    }
    if (i < N) rowptr[i] = bpref[blockIdx.x] + s[threadIdx.x] - v;
    if (blockIdx.x == 0 && threadIdx.x == 0) rowptr[N] = E;
}

__global__ __launch_bounds__(256) void k_scatter(const int* __restrict__ src,
                                                 const int* __restrict__ dst,
                                                 const float* __restrict__ ew,
                                                 const int* __restrict__ rowptr,
                                                 int* __restrict__ cursor,
                                                 int2* __restrict__ csr, int E)
{
    int e = blockIdx.x * 256 + threadIdx.x;
    if (e < E) {
        int d = dst[e];
        int pos = rowptr[d] + atomicAdd(&cursor[d], 1);
        int2 v;
        v.x = src[e];
        v.y = __float_as_int(ew[e]);
        csr[pos] = v;
    }
}

// ---- layer 1: agg1[n] = sum ew*x[src]; pack axn = {agg1, x} ---------------
__global__ __launch_bounds__(256) void k_agg1(const int2* __restrict__ csr,
                                              const int* __restrict__ rowptr,
                                              const float* __restrict__ x,
                                              float2* __restrict__ axn, int N)
{
    int n = blockIdx.x * 256 + threadIdx.x;
    if (n >= N) return;
    int b = rowptr[n], en = rowptr[n + 1];
    float a = 0.f;
    for (int e = b; e < en; ++e) {
        int2 sw = csr[e];
        a = fmaf(__int_as_float(sw.y), x[sw.x], a);
    }
    axn[n] = make_float2(a, x[n]);
}

// ---- layer 2 aggregation: wave per node, lane = channel --------------------
__global__ __launch_bounds__(256) void k_agg2(const int2* __restrict__ csr,
                                              const int* __restrict__ rowptr,
                                              const float2* __restrict__ axn,
                                              const float* __restrict__ W1_rel,
                                              const float* __restrict__ b1,
                                              const float* __restrict__ W1_root,
                                              float* __restrict__ agg2, int N)
{
    int n = (blockIdx.x * 256 + threadIdx.x) >> 6;
    int lane = threadIdx.x & 63;
    if (n >= N) return;
    float wrel = W1_rel[lane], wroot = W1_root[lane], bj = b1[lane];
    int b = rowptr[n], en = rowptr[n + 1];
    float acc = 0.f;
    for (int e = b; e < en; ++e) {
        int2 sw = csr[e];
        float w = __int_as_float(sw.y);
        float2 ax = axn[sw.x];
        float h = fmaxf(fmaf(ax.x, wrel, fmaf(ax.y, wroot, bj)), 0.f);
        acc = fmaf(w, h, acc);
    }
    agg2[(size_t)n * 64 + lane] = acc;
}

// ---- layer-2 node GEMM + layer-3 fold: quad-per-node -----------------------
// 4 threads per node; thread p owns k in [32p, 32p+32) of the 128-long
// combined vector v = { agg2[n][0..63], h1[n][0..63] }.
// h2[j] = relu( sum_k v[k]*Wc[j][k] + b2[j] );  z[n][c] = sum_j h2[j]*MC[j][c]
__global__ __launch_bounds__(256) void k_node2(const float* __restrict__ agg2,
                                               const float2* __restrict__ axn,
                                               const float* __restrict__ Wc,    // [64][128]
                                               const float* __restrict__ b2,
                                               const float* __restrict__ W1_rel,
                                               const float* __restrict__ b1,
                                               const float* __restrict__ W1_root,
                                               const float* __restrict__ MCf,   // [64][4]
                                               float* __restrict__ z, int N)
{
    int gt = blockIdx.x * 256 + threadIdx.x;
    int n = gt >> 2;
    int p = gt & 3;
    if (n >= N) return;

    // Load / build this thread's quarter of the combined vector (32 floats).
    float4 v[8];
    if (p < 2) {
        const float4* ag = reinterpret_cast<const float4*>(agg2 + (size_t)n * 64 + p * 32);
#pragma unroll
        for (int q = 0; q < 8; ++q) v[q] = ag[q];
    } else {
        float2 ax = axn[n];
        int k0 = (p - 2) * 32;
#pragma unroll
        for (int q = 0; q < 8; ++q) {
            float4 wr = ld4(&W1_rel[k0 + q * 4]);
            float4 wo = ld4(&W1_root[k0 + q * 4]);
            float4 bb = ld4(&b1[k0 + q * 4]);
            v[q].x = fmaxf(fmaf(ax.x, wr.x, fmaf(ax.y, wo.x, bb.x)), 0.f);
            v[q].y = fmaxf(fmaf(ax.x, wr.y, fmaf(ax.y, wo.y, bb.y)), 0.f);
            v[q].z = fmaxf(fmaf(ax.x, wr.z, fmaf(ax.y, wo.z, bb.z)), 0.f);
            v[q].w = fmaxf(fmaf(ax.x, wr.w, fmaf(ax.y, wo.w, bb.w)), 0.f);
        }
    }

    const float4* wbase = reinterpret_cast<const float4*>(Wc + p * 32);
    float zacc = 0.f;

#pragma unroll 2
    for (int j = 0; j < 64; ++j) {
        const float4* wq = wbase + j * 32;   // this quarter of row j (L1-hot, 32KB total)
        float s0 = 0.f, s1 = 0.f;
#pragma unroll
        for (int q = 0; q < 8; q += 2) {
            float4 w0 = wq[q], w1 = wq[q + 1];
            s0 = fmaf(v[q].x, w0.x, fmaf(v[q].y, w0.y, fmaf(v[q].z, w0.z, fmaf(v[q].w, w0.w, s0))));
            s1 = fmaf(v[q + 1].x, w1.x, fmaf(v[q + 1].y, w1.y, fmaf(v[q + 1].z, w1.z, fmaf(v[q + 1].w, w1.w, s1))));
        }
        float s = s0 + s1;
        s += __shfl_xor(s, 1);
        s += __shfl_xor(s, 2);
        float h2 = fmaxf(s + b2[j], 0.f);           // b2[j]: wave-uniform -> s_load
        zacc = fmaf(h2, MCf[j * 4 + p], zacc);      // 16B line broadcast, L1-hot
    }
    z[(size_t)n * 4 + p] = zacc;                    // quad writes contiguous 16B
}

// ---- pool: per-node CSR gather of edge term + node term, LDS-binned --------
__global__ __launch_bounds__(256) void k_pool(const int2* __restrict__ csr,
                                              const int* __restrict__ rowptr,
                                              const int* __restrict__ batch,
                                              const float* __restrict__ z4,
                                              float* __restrict__ gacc, int N, int G)
{
    extern __shared__ float lds[];  // [G][5]
    for (int i = threadIdx.x; i < 5 * G; i += 256) lds[i] = 0.f;
    __syncthreads();

    int gt = blockIdx.x * 256 + threadIdx.x;
    int TT = gridDim.x * 256;
    for (int n = gt; n < N; n += TT) {
        int bg = batch[n];
        int b = rowptr[n], en = rowptr[n + 1];
        float s0 = 0.f, s1 = 0.f;
        for (int e = b; e < en; ++e) {
            int2 sw = csr[e];
            float w = __int_as_float(sw.y);
            float2 zz = *reinterpret_cast<const float2*>(&z4[(size_t)sw.x * 4]);
            s0 = fmaf(w, zz.x, s0);
            s1 = fmaf(w, zz.y, s1);
        }
        float2 zw = *reinterpret_cast<const float2*>(&z4[(size_t)n * 4 + 2]);
        atomicAdd(&lds[bg * 5 + 0], s0);
        atomicAdd(&lds[bg * 5 + 1], s1);
        atomicAdd(&lds[bg * 5 + 2], zw.x);
        atomicAdd(&lds[bg * 5 + 3], zw.y);
        atomicAdd(&lds[bg * 5 + 4], 1.0f);
    }
    __syncthreads();
    for (int i = threadIdx.x; i < 5 * G; i += 256) {
        float v = lds[i];
        if (v != 0.f) atomicAdd(&gacc[i], v);
    }
}

__global__ void k_final(const float* __restrict__ gacc, const float* __restrict__ b3W,
                        const float* __restrict__ b_lin, float* __restrict__ out, int G)
{
    int t = blockIdx.x * blockDim.x + threadIdx.x;
    if (t < G * 2) {
        int g = t >> 1, c = t & 1;
        float cnt = gacc[g * 5 + 4];
        float s = gacc[g * 5 + c] + gacc[g * 5 + 2 + c] + cnt * b3W[c];
        out[t] = s / fmaxf(cnt, 1.f) + b_lin[c];
    }
}

extern "C" void kernel_launch(void* const* d_in, const int* in_sizes, int n_in,
                              void* d_out, int out_size, void* d_ws, size_t ws_size,
                              hipStream_t stream)
{
    const float* x       = (const float*)d_in[0];
    const int*   ei      = (const int*)  d_in[1];
    const int*   batch   = (const int*)  d_in[2];
    const float* ew      = (const float*)d_in[3];
    const float* W1_rel  = (const float*)d_in[4];
    const float* b1      = (const float*)d_in[5];
    const float* W1_root = (const float*)d_in[6];
    const float* W2_rel  = (const float*)d_in[7];
    const float* b2      = (const float*)d_in[8];
    const float* W2_root = (const float*)d_in[9];
    const float* W3_rel  = (const float*)d_in[10];
    const float* b3      = (const float*)d_in[11];
    const float* W3_root = (const float*)d_in[12];
    const float* W_lin   = (const float*)d_in[13];
    const float* b_lin   = (const float*)d_in[14];
    float* out = (float*)d_out;

    const int N = in_sizes[0];
    const int E = in_sizes[3];
    const int G = out_size / 2;
    const int NB = (N + 255) / 256;
    const int* src = ei;
    const int* dst = ei + E;

    char* wsb = (char*)d_ws;
    size_t o = 0;
    auto take = [&](size_t bytes) -> char* {
        char* p = wsb + o;
        o += (bytes + 15) & ~(size_t)15;
        return p;
    };
    int*    deg    = (int*)   take((size_t)N * 4);
    int*    cursor = (int*)   take((size_t)N * 4);
    float*  gacc   = (float*) take((size_t)G * 5 * 4);
    size_t  zero_bytes = o;
    int*    rowptr = (int*)   take((size_t)(N + 1) * 4);
    int*    bsum   = (int*)   take((size_t)NB * 4);
    int*    bpref  = (int*)   take((size_t)NB * 4);
    int2*   csr    = (int2*)  take((size_t)E * 8);
    float2* axn    = (float2*)take((size_t)N * 8);
    float*  agg2   = (float*) take((size_t)N * 64 * 4);
    float*  z      = (float*) take((size_t)N * 16);
    float4* MC4    = (float4*)take(64 * 16);
    float*  b3W    = (float*) take(4 * 4);
    float*  Wc     = (float*) take(8192 * 4);

    hipMemsetAsync(d_ws, 0, zero_bytes, stream);

    hipLaunchKernelGGL(k_small, dim3(1), dim3(256), 0, stream,
                       W3_rel, b3, W3_root, W_lin, W2_rel, W2_root,
                       MC4, b3W, Wc);

    hipLaunchKernelGGL(k_hist, dim3((E + 255) / 256), dim3(256), 0, stream, dst, deg, E);
    hipLaunchKernelGGL(k_blocksum, dim3(NB), dim3(256), 0, stream, deg, bsum, N);
    hipLaunchKernelGGL(k_scanbsum, dim3(1), dim3(256), 0, stream, bsum, bpref, NB);
    hipLaunchKernelGGL(k_scan3, dim3(NB), dim3(256), 0, stream, deg, bpref, rowptr, N, E);
    hipLaunchKernelGGL(k_scatter, dim3((E + 255) / 256), dim3(256), 0, stream,
                       src, dst, ew, rowptr, cursor, csr, E);

    hipLaunchKernelGGL(k_agg1, dim3(NB), dim3(256), 0, stream, csr, rowptr, x, axn, N);

    hipLaunchKernelGGL(k_agg2, dim3((N * 64 + 255) / 256), dim3(256), 0, stream,
                       csr, rowptr, axn, W1_rel, b1, W1_root, agg2, N);

    hipLaunchKernelGGL(k_node2, dim3(((size_t)N * 4 + 255) / 256), dim3(256), 0, stream,
                       agg2, axn, Wc, b2, W1_rel, b1, W1_root,
                       (const float*)MC4, z, N);

    hipLaunchKernelGGL(k_pool, dim3(512), dim3(256), 5 * G * sizeof(float), stream,
                       csr, rowptr, batch, z, gacc, N, G);

    hipLaunchKernelGGL(k_final, dim3((G * 2 + 255) / 256), dim3(256), 0, stream,
                       gacc, b3W, b_lin, out, G);
}

// Round 5
// 287.844 us; speedup vs baseline: 2.2941x; 2.2941x over previous
//
#include <hip/hip_runtime.h>

// ---------------------------------------------------------------------------
// GNN: 3x GraphConv(H=64) + global_mean_pool + Linear(64->2)
// N=100000, E=1200000, G=256, C_IN=1, C_OUT=2
//
// Round-5: k_node2 -> lane=node, j register-blocked, weights via the SCALAR
// path (wave-uniform addresses -> s_load; round-4 proved per-lane weight
// loads are L1-BW death). agg2 tile in LDS [128][65] (conflict-free),
// h1 recomputed from axn, j split across wave pairs, LDS combine.
// ---------------------------------------------------------------------------

static __device__ __forceinline__ float4 ld4(const float* p) {
    return *reinterpret_cast<const float4*>(p);
}

// Precompute: MC4[j] = { Mrel[j][0], Mrel[j][1], Mroot[j][0], Mroot[j][1] },
// b3W[c] = b3 @ W_lin.
__global__ void k_small(const float* __restrict__ W3_rel, const float* __restrict__ b3,
                        const float* __restrict__ W3_root, const float* __restrict__ W_lin,
                        float4* __restrict__ MC4, float* __restrict__ b3W)
{
    int t = threadIdx.x;
    if (t < 64) {
        float sr0 = 0.f, sr1 = 0.f, so0 = 0.f, so1 = 0.f;
        for (int k = 0; k < 64; ++k) {
            float wl0 = W_lin[k * 2 + 0], wl1 = W_lin[k * 2 + 1];
            sr0 += W3_rel[t * 64 + k] * wl0;
            sr1 += W3_rel[t * 64 + k] * wl1;
            so0 += W3_root[t * 64 + k] * wl0;
            so1 += W3_root[t * 64 + k] * wl1;
        }
        MC4[t] = make_float4(sr0, sr1, so0, so1);
    }
    if (t < 2) {
        float s = 0.f;
        for (int k = 0; k < 64; ++k) s += b3[k] * W_lin[k * 2 + t];
        b3W[t] = s;
    }
}

// ---- CSR build -------------------------------------------------------------
__global__ __launch_bounds__(256) void k_hist(const int* __restrict__ dst,
                                              int* __restrict__ deg, int E)
{
    int e = blockIdx.x * 256 + threadIdx.x;
    if (e < E) atomicAdd(&deg[dst[e]], 1);
}

__global__ __launch_bounds__(256) void k_blocksum(const int* __restrict__ deg,
                                                  int* __restrict__ bsum, int N)
{
    __shared__ int s[256];
    int i = blockIdx.x * 256 + threadIdx.x;
    s[threadIdx.x] = (i < N) ? deg[i] : 0;
    __syncthreads();
    for (int o = 128; o > 0; o >>= 1) {
        if (threadIdx.x < o) s[threadIdx.x] += s[threadIdx.x + o];
        __syncthreads();
    }
    if (threadIdx.x == 0) bsum[blockIdx.x] = s[0];
}

__global__ __launch_bounds__(256) void k_scanbsum(const int* __restrict__ bsum,
                                                  int* __restrict__ bpref, int nb)
{
    __shared__ int s[256];
    __shared__ int carry;
    if (threadIdx.x == 0) carry = 0;
    __syncthreads();
    for (int base = 0; base < nb; base += 256) {
        int i = base + threadIdx.x;
        int v = (i < nb) ? bsum[i] : 0;
        s[threadIdx.x] = v;
        __syncthreads();
        for (int off = 1; off < 256; off <<= 1) {
            int t = (threadIdx.x >= off) ? s[threadIdx.x - off] : 0;
            __syncthreads();
            s[threadIdx.x] += t;
            __syncthreads();
        }
        if (i < nb) bpref[i] = carry + s[threadIdx.x] - v;  // exclusive
        __syncthreads();
        if (threadIdx.x == 0) carry += s[255];
        __syncthreads();
    }
}

__global__ __launch_bounds__(256) void k_scan3(const int* __restrict__ deg,
                                               const int* __restrict__ bpref,
                                               int* __restrict__ rowptr, int N, int E)
{
    __shared__ int s[256];
    int i = blockIdx.x * 256 + threadIdx.x;
    int v = (i < N) ? deg[i] : 0;
    s[threadIdx.x] = v;
    __syncthreads();
    for (int off = 1; off < 256; off <<= 1) {
        int t = (threadIdx.x >= off) ? s[threadIdx.x - off] : 0;
        __syncthreads();
        s[threadIdx.x] += t;
        __syncthreads();
    }
    if (i < N) rowptr[i] = bpref[blockIdx.x] + s[threadIdx.x] - v;
    if (blockIdx.x == 0 && threadIdx.x == 0) rowptr[N] = E;
}

__global__ __launch_bounds__(256) void k_scatter(const int* __restrict__ src,
                                                 const int* __restrict__ dst,
                                                 const float* __restrict__ ew,
                                                 const int* __restrict__ rowptr,
                                                 int* __restrict__ cursor,
                                                 int2* __restrict__ csr, int E)
{
    int e = blockIdx.x * 256 + threadIdx.x;
    if (e < E) {
        int d = dst[e];
        int pos = rowptr[d] + atomicAdd(&cursor[d], 1);
        int2 v;
        v.x = src[e];
        v.y = __float_as_int(ew[e]);
        csr[pos] = v;
    }
}

// ---- layer 1: agg1[n] = sum ew*x[src]; pack axn = {agg1, x} ---------------
__global__ __launch_bounds__(256) void k_agg1(const int2* __restrict__ csr,
                                              const int* __restrict__ rowptr,
                                              const float* __restrict__ x,
                                              float2* __restrict__ axn, int N)
{
    int n = blockIdx.x * 256 + threadIdx.x;
    if (n >= N) return;
    int b = rowptr[n], en = rowptr[n + 1];
    float a = 0.f;
    for (int e = b; e < en; ++e) {
        int2 sw = csr[e];
        a = fmaf(__int_as_float(sw.y), x[sw.x], a);
    }
    axn[n] = make_float2(a, x[n]);
}

// ---- layer 2 aggregation: wave per node, lane = channel --------------------
__global__ __launch_bounds__(256) void k_agg2(const int2* __restrict__ csr,
                                              const int* __restrict__ rowptr,
                                              const float2* __restrict__ axn,
                                              const float* __restrict__ W1_rel,
                                              const float* __restrict__ b1,
                                              const float* __restrict__ W1_root,
                                              float* __restrict__ agg2, int N)
{
    int n = (blockIdx.x * 256 + threadIdx.x) >> 6;
    int lane = threadIdx.x & 63;
    if (n >= N) return;
    float wrel = W1_rel[lane], wroot = W1_root[lane], bj = b1[lane];
    int b = rowptr[n], en = rowptr[n + 1];
    float acc = 0.f;
    for (int e = b; e < en; ++e) {
        int2 sw = csr[e];
        float w = __int_as_float(sw.y);
        float2 ax = axn[sw.x];
        float h = fmaxf(fmaf(ax.x, wrel, fmaf(ax.y, wroot, bj)), 0.f);
        acc = fmaf(w, h, acc);
    }
    agg2[(size_t)n * 64 + lane] = acc;
}

// ---- layer-2 node GEMM + layer-3 fold --------------------------------------
// Block = 128 nodes (2 node-groups x 64 lanes), 4 waves. Wave handles 64
// nodes x 32 j-cols (j-half hs, wave-uniform via readfirstlane -> weights
// come from the scalar path). agg2 tile in LDS [128][65]; h1 part from axn.
__global__ __launch_bounds__(256) void k_node2(const float* __restrict__ agg2,
                                               const float2* __restrict__ axn,
                                               const float* __restrict__ W2_rel,
                                               const float* __restrict__ W2_root,
                                               const float* __restrict__ b2,
                                               const float* __restrict__ W1_rel,
                                               const float* __restrict__ b1,
                                               const float* __restrict__ W1_root,
                                               const float* __restrict__ MCf,   // [64][4]
                                               float2* __restrict__ z01,
                                               float2* __restrict__ z23, int N)
{
    __shared__ float As[128 * 65];

    const int t = threadIdx.x;
    const int n0 = blockIdx.x * 128;

    // Stage agg2 tile: [nl][k] with stride 65 (bank-conflict-free).
#pragma unroll
    for (int it = 0; it < 8; ++it) {
        int idx = it * 256 + t;            // 0..2047
        int nl = idx >> 4, q4 = (idx & 15) << 2;
        int n = n0 + nl;
        float4 a = (n < N) ? ld4(&agg2[(size_t)n * 64 + q4])
                           : make_float4(0.f, 0.f, 0.f, 0.f);
        float* row = &As[nl * 65 + q4];
        row[0] = a.x; row[1] = a.y; row[2] = a.z; row[3] = a.w;
    }
    __syncthreads();

    const int lane = t & 63;
    const int g = (t >> 7) & 1;                                    // node-group
    const int hs = __builtin_amdgcn_readfirstlane((t >> 6) & 1);   // j-half, SGPR
    const int nl = g * 64 + lane;
    const int n = n0 + nl;
    float2 ax = (n < N) ? axn[n] : make_float2(0.f, 0.f);

    float4 acc[8];
#pragma unroll
    for (int q = 0; q < 8; ++q) acc[q] = make_float4(0.f, 0.f, 0.f, 0.f);

    const float* Asr = &As[nl * 65];

    // ---- A part: k = 0..63, v_k from LDS, weights scalar ----
    for (int c = 0; c < 8; ++c) {          // 8 chunks of 8 k
        float a_[8];
#pragma unroll
        for (int i = 0; i < 8; ++i) a_[i] = Asr[c * 8 + i];
#pragma unroll
        for (int i = 0; i < 8; ++i) {
            const float* wr = &W2_rel[(size_t)(c * 8 + i) * 64 + hs * 32];
#pragma unroll
            for (int q = 0; q < 8; ++q) {
                float4 w = ld4(wr + q * 4);
                acc[q].x = fmaf(a_[i], w.x, acc[q].x);
                acc[q].y = fmaf(a_[i], w.y, acc[q].y);
                acc[q].z = fmaf(a_[i], w.z, acc[q].z);
                acc[q].w = fmaf(a_[i], w.w, acc[q].w);
            }
        }
    }

    // ---- H part: k = 0..63, h_k = relu(ax.x*W1_rel[k] + ax.y*W1_root[k] + b1[k])
    for (int c = 0; c < 8; ++c) {
        int k0 = c * 8;
        float4 w1ra = ld4(&W1_rel[k0]),  w1rb = ld4(&W1_rel[k0 + 4]);
        float4 w1oa = ld4(&W1_root[k0]), w1ob = ld4(&W1_root[k0 + 4]);
        float4 b1a  = ld4(&b1[k0]),      b1b  = ld4(&b1[k0 + 4]);
        float hk[8];
        hk[0] = fmaxf(fmaf(ax.x, w1ra.x, fmaf(ax.y, w1oa.x, b1a.x)), 0.f);
        hk[1] = fmaxf(fmaf(ax.x, w1ra.y, fmaf(ax.y, w1oa.y, b1a.y)), 0.f);
        hk[2] = fmaxf(fmaf(ax.x, w1ra.z, fmaf(ax.y, w1oa.z, b1a.z)), 0.f);
        hk[3] = fmaxf(fmaf(ax.x, w1ra.w, fmaf(ax.y, w1oa.w, b1a.w)), 0.f);
        hk[4] = fmaxf(fmaf(ax.x, w1rb.x, fmaf(ax.y, w1ob.x, b1b.x)), 0.f);
        hk[5] = fmaxf(fmaf(ax.x, w1rb.y, fmaf(ax.y, w1ob.y, b1b.y)), 0.f);
        hk[6] = fmaxf(fmaf(ax.x, w1rb.z, fmaf(ax.y, w1ob.z, b1b.z)), 0.f);
        hk[7] = fmaxf(fmaf(ax.x, w1rb.w, fmaf(ax.y, w1ob.w, b1b.w)), 0.f);
#pragma unroll
        for (int i = 0; i < 8; ++i) {
            const float* wo = &W2_root[(size_t)(k0 + i) * 64 + hs * 32];
#pragma unroll
            for (int q = 0; q < 8; ++q) {
                float4 w = ld4(wo + q * 4);
                acc[q].x = fmaf(hk[i], w.x, acc[q].x);
                acc[q].y = fmaf(hk[i], w.y, acc[q].y);
                acc[q].z = fmaf(hk[i], w.z, acc[q].z);
                acc[q].w = fmaf(hk[i], w.w, acc[q].w);
            }
        }
    }

    // ---- epilogue: bias + relu + fold to z partials over this j-half ----
    float z0 = 0.f, z1 = 0.f, z2 = 0.f, z3 = 0.f;
    const float* b2h = &b2[hs * 32];
#pragma unroll
    for (int q = 0; q < 8; ++q) {
        float4 bq = ld4(b2h + q * 4);
        int jb = hs * 32 + q * 4;
        float h2;
        h2 = fmaxf(acc[q].x + bq.x, 0.f);
        { const float* m = &MCf[(jb + 0) * 4];
          z0 = fmaf(h2, m[0], z0); z1 = fmaf(h2, m[1], z1);
          z2 = fmaf(h2, m[2], z2); z3 = fmaf(h2, m[3], z3); }
        h2 = fmaxf(acc[q].y + bq.y, 0.f);
        { const float* m = &MCf[(jb + 1) * 4];
          z0 = fmaf(h2, m[0], z0); z1 = fmaf(h2, m[1], z1);
          z2 = fmaf(h2, m[2], z2); z3 = fmaf(h2, m[3], z3); }
        h2 = fmaxf(acc[q].z + bq.z, 0.f);
        { const float* m = &MCf[(jb + 2) * 4];
          z0 = fmaf(h2, m[0], z0); z1 = fmaf(h2, m[1], z1);
          z2 = fmaf(h2, m[2], z2); z3 = fmaf(h2, m[3], z3); }
        h2 = fmaxf(acc[q].w + bq.w, 0.f);
        { const float* m = &MCf[(jb + 3) * 4];
          z0 = fmaf(h2, m[0], z0); z1 = fmaf(h2, m[1], z1);
          z2 = fmaf(h2, m[2], z2); z3 = fmaf(h2, m[3], z3); }
    }

    // ---- combine the two j-halves via LDS (reuse As) ----
    __syncthreads();                       // everyone done reading As
    float* zs = As;                        // [128][2][4]
    *reinterpret_cast<float4*>(&zs[(nl * 2 + hs) * 4]) = make_float4(z0, z1, z2, z3);
    __syncthreads();
    if (hs == 0 && n < N) {
        float4 p0 = *reinterpret_cast<float4*>(&zs[(nl * 2 + 0) * 4]);
        float4 p1 = *reinterpret_cast<float4*>(&zs[(nl * 2 + 1) * 4]);
        z01[n] = make_float2(p0.x + p1.x, p0.y + p1.y);
        z23[n] = make_float2(p0.z + p1.z, p0.w + p1.w);
    }
}

// ---- pool: per-node CSR gather of edge term + node term, LDS-binned --------
__global__ __launch_bounds__(256) void k_pool(const int2* __restrict__ csr,
                                              const int* __restrict__ rowptr,
                                              const int* __restrict__ batch,
                                              const float2* __restrict__ z01,
                                              const float2* __restrict__ z23,
                                              float* __restrict__ gacc, int N, int G)
{
    extern __shared__ float lds[];  // [G][5]
    for (int i = threadIdx.x; i < 5 * G; i += 256) lds[i] = 0.f;
    __syncthreads();

    int gt = blockIdx.x * 256 + threadIdx.x;
    int TT = gridDim.x * 256;
    for (int n = gt; n < N; n += TT) {
        int bg = batch[n];
        int b = rowptr[n], en = rowptr[n + 1];
        float s0 = 0.f, s1 = 0.f;
        for (int e = b; e < en; ++e) {
            int2 sw = csr[e];
            float w = __int_as_float(sw.y);
            float2 zz = z01[sw.x];
            s0 = fmaf(w, zz.x, s0);
            s1 = fmaf(w, zz.y, s1);
        }
        float2 zw = z23[n];
        atomicAdd(&lds[bg * 5 + 0], s0);
        atomicAdd(&lds[bg * 5 + 1], s1);
        atomicAdd(&lds[bg * 5 + 2], zw.x);
        atomicAdd(&lds[bg * 5 + 3], zw.y);
        atomicAdd(&lds[bg * 5 + 4], 1.0f);
    }
    __syncthreads();
    for (int i = threadIdx.x; i < 5 * G; i += 256) {
        float v = lds[i];
        if (v != 0.f) atomicAdd(&gacc[i], v);
    }
}

__global__ void k_final(const float* __restrict__ gacc, const float* __restrict__ b3W,
                        const float* __restrict__ b_lin, float* __restrict__ out, int G)
{
    int t = blockIdx.x * blockDim.x + threadIdx.x;
    if (t < G * 2) {
        int g = t >> 1, c = t & 1;
        float cnt = gacc[g * 5 + 4];
        float s = gacc[g * 5 + c] + gacc[g * 5 + 2 + c] + cnt * b3W[c];
        out[t] = s / fmaxf(cnt, 1.f) + b_lin[c];
    }
}

extern "C" void kernel_launch(void* const* d_in, const int* in_sizes, int n_in,
                              void* d_out, int out_size, void* d_ws, size_t ws_size,
                              hipStream_t stream)
{
    const float* x       = (const float*)d_in[0];
    const int*   ei      = (const int*)  d_in[1];
    const int*   batch   = (const int*)  d_in[2];
    const float* ew      = (const float*)d_in[3];
    const float* W1_rel  = (const float*)d_in[4];
    const float* b1      = (const float*)d_in[5];
    const float* W1_root = (const float*)d_in[6];
    const float* W2_rel  = (const float*)d_in[7];
    const float* b2      = (const float*)d_in[8];
    const float* W2_root = (const float*)d_in[9];
    const float* W3_rel  = (const float*)d_in[10];
    const float* b3      = (const float*)d_in[11];
    const float* W3_root = (const float*)d_in[12];
    const float* W_lin   = (const float*)d_in[13];
    const float* b_lin   = (const float*)d_in[14];
    float* out = (float*)d_out;

    const int N = in_sizes[0];
    const int E = in_sizes[3];
    const int G = out_size / 2;
    const int NB = (N + 255) / 256;
    const int* src = ei;
    const int* dst = ei + E;

    char* wsb = (char*)d_ws;
    size_t o = 0;
    auto take = [&](size_t bytes) -> char* {
        char* p = wsb + o;
        o += (bytes + 15) & ~(size_t)15;
        return p;
    };
    int*    deg    = (int*)   take((size_t)N * 4);
    int*    cursor = (int*)   take((size_t)N * 4);
    float*  gacc   = (float*) take((size_t)G * 5 * 4);
    size_t  zero_bytes = o;
    int*    rowptr = (int*)   take((size_t)(N + 1) * 4);
    int*    bsum   = (int*)   take((size_t)NB * 4);
    int*    bpref  = (int*)   take((size_t)NB * 4);
    int2*   csr    = (int2*)  take((size_t)E * 8);
    float2* axn    = (float2*)take((size_t)N * 8);
    float*  agg2   = (float*) take((size_t)N * 64 * 4);
    float2* z01    = (float2*)take((size_t)N * 8);
    float2* z23    = (float2*)take((size_t)N * 8);
    float4* MC4    = (float4*)take(64 * 16);
    float*  b3W    = (float*) take(4 * 4);

    hipMemsetAsync(d_ws, 0, zero_bytes, stream);

    hipLaunchKernelGGL(k_small, dim3(1), dim3(256), 0, stream,
                       W3_rel, b3, W3_root, W_lin, MC4, b3W);

    hipLaunchKernelGGL(k_hist, dim3((E + 255) / 256), dim3(256), 0, stream, dst, deg, E);
    hipLaunchKernelGGL(k_blocksum, dim3(NB), dim3(256), 0, stream, deg, bsum, N);
    hipLaunchKernelGGL(k_scanbsum, dim3(1), dim3(256), 0, stream, bsum, bpref, NB);
    hipLaunchKernelGGL(k_scan3, dim3(NB), dim3(256), 0, stream, deg, bpref, rowptr, N, E);
    hipLaunchKernelGGL(k_scatter, dim3((E + 255) / 256), dim3(256), 0, stream,
                       src, dst, ew, rowptr, cursor, csr, E);

    hipLaunchKernelGGL(k_agg1, dim3(NB), dim3(256), 0, stream, csr, rowptr, x, axn, N);

    hipLaunchKernelGGL(k_agg2, dim3((N * 64 + 255) / 256), dim3(256), 0, stream,
                       csr, rowptr, axn, W1_rel, b1, W1_root, agg2, N);

    hipLaunchKernelGGL(k_node2, dim3((N + 127) / 128), dim3(256), 0, stream,
                       agg2, axn, W2_rel, W2_root, b2, W1_rel, b1, W1_root,
                       (const float*)MC4, z01, z23, N);

    hipLaunchKernelGGL(k_pool, dim3(512), dim3(256), 5 * G * sizeof(float), stream,
                       csr, rowptr, batch, z01, z23, gacc, N, G);

    hipLaunchKernelGGL(k_final, dim3((G * 2 + 255) / 256), dim3(256), 0, stream,
                       gacc, b3W, b_lin, out, G);
}

// Round 6
// 216.723 us; speedup vs baseline: 3.0469x; 1.3282x over previous
//
#include <hip/hip_runtime.h>

// ---------------------------------------------------------------------------
// GNN: 3x GraphConv(H=64) + global_mean_pool + Linear(64->2)
// N=100000, E=1200000, G=256, C_IN=1, C_OUT=2
//
// Round-6: kill the dependent-broadcast-load latency in all CSR gather loops.
//  - k_agg2: lane i loads edge b+i (coalesced), inner loop broadcasts lane
//    i's {w, a, x} via v_readlane (scalar path, no memory). 7 instrs/edge.
//  - k_agg1 / k_pool: 4 threads per node, strided edges, shfl_xor combine
//    (4 independent load chains instead of 1).
// ---------------------------------------------------------------------------

static __device__ __forceinline__ float4 ld4(const float* p) {
    return *reinterpret_cast<const float4*>(p);
}

static __device__ __forceinline__ float rdlane(float v, int i) {
    return __int_as_float(__builtin_amdgcn_readlane(__float_as_int(v), i));
}

// Precompute: MC4[j] = { Mrel[j][0], Mrel[j][1], Mroot[j][0], Mroot[j][1] },
// b3W[c] = b3 @ W_lin.
__global__ void k_small(const float* __restrict__ W3_rel, const float* __restrict__ b3,
                        const float* __restrict__ W3_root, const float* __restrict__ W_lin,
                        float4* __restrict__ MC4, float* __restrict__ b3W)
{
    int t = threadIdx.x;
    if (t < 64) {
        float sr0 = 0.f, sr1 = 0.f, so0 = 0.f, so1 = 0.f;
        for (int k = 0; k < 64; ++k) {
            float wl0 = W_lin[k * 2 + 0], wl1 = W_lin[k * 2 + 1];
            sr0 += W3_rel[t * 64 + k] * wl0;
            sr1 += W3_rel[t * 64 + k] * wl1;
            so0 += W3_root[t * 64 + k] * wl0;
            so1 += W3_root[t * 64 + k] * wl1;
        }
        MC4[t] = make_float4(sr0, sr1, so0, so1);
    }
    if (t < 2) {
        float s = 0.f;
        for (int k = 0; k < 64; ++k) s += b3[k] * W_lin[k * 2 + t];
        b3W[t] = s;
    }
}

// ---- CSR build -------------------------------------------------------------
__global__ __launch_bounds__(256) void k_hist(const int* __restrict__ dst,
                                              int* __restrict__ deg, int E)
{
    int e = blockIdx.x * 256 + threadIdx.x;
    if (e < E) atomicAdd(&deg[dst[e]], 1);
}

__global__ __launch_bounds__(256) void k_blocksum(const int* __restrict__ deg,
                                                  int* __restrict__ bsum, int N)
{
    __shared__ int s[256];
    int i = blockIdx.x * 256 + threadIdx.x;
    s[threadIdx.x] = (i < N) ? deg[i] : 0;
    __syncthreads();
    for (int o = 128; o > 0; o >>= 1) {
        if (threadIdx.x < o) s[threadIdx.x] += s[threadIdx.x + o];
        __syncthreads();
    }
    if (threadIdx.x == 0) bsum[blockIdx.x] = s[0];
}

__global__ __launch_bounds__(256) void k_scanbsum(const int* __restrict__ bsum,
                                                  int* __restrict__ bpref, int nb)
{
    __shared__ int s[256];
    __shared__ int carry;
    if (threadIdx.x == 0) carry = 0;
    __syncthreads();
    for (int base = 0; base < nb; base += 256) {
        int i = base + threadIdx.x;
        int v = (i < nb) ? bsum[i] : 0;
        s[threadIdx.x] = v;
        __syncthreads();
        for (int off = 1; off < 256; off <<= 1) {
            int t = (threadIdx.x >= off) ? s[threadIdx.x - off] : 0;
            __syncthreads();
            s[threadIdx.x] += t;
            __syncthreads();
        }
        if (i < nb) bpref[i] = carry + s[threadIdx.x] - v;  // exclusive
        __syncthreads();
        if (threadIdx.x == 0) carry += s[255];
        __syncthreads();
    }
}

__global__ __launch_bounds__(256) void k_scan3(const int* __restrict__ deg,
                                               const int* __restrict__ bpref,
                                               int* __restrict__ rowptr, int N, int E)
{
    __shared__ int s[256];
    int i = blockIdx.x * 256 + threadIdx.x;
    int v = (i < N) ? deg[i] : 0;
    s[threadIdx.x] = v;
    __syncthreads();
    for (int off = 1; off < 256; off <<= 1) {
        int t = (threadIdx.x >= off) ? s[threadIdx.x - off] : 0;
        __syncthreads();
        s[threadIdx.x] += t;
        __syncthreads();
    }
    if (i < N) rowptr[i] = bpref[blockIdx.x] + s[threadIdx.x] - v;
    if (blockIdx.x == 0 && threadIdx.x == 0) rowptr[N] = E;
}

__global__ __launch_bounds__(256) void k_scatter(const int* __restrict__ src,
                                                 const int* __restrict__ dst,
                                                 const float* __restrict__ ew,
                                                 const int* __restrict__ rowptr,
                                                 int* __restrict__ cursor,
                                                 int2* __restrict__ csr, int E)
{
    int e = blockIdx.x * 256 + threadIdx.x;
    if (e < E) {
        int d = dst[e];
        int pos = rowptr[d] + atomicAdd(&cursor[d], 1);
        int2 v;
        v.x = src[e];
        v.y = __float_as_int(ew[e]);
        csr[pos] = v;
    }
}

// ---- layer 1: agg1[n] = sum ew*x[src]; pack axn = {agg1, x} ----------------
// 4 threads per node: 4 independent load chains, shfl_xor combine.
__global__ __launch_bounds__(256) void k_agg1(const int2* __restrict__ csr,
                                              const int* __restrict__ rowptr,
                                              const float* __restrict__ x,
                                              float2* __restrict__ axn, int N)
{
    int gt = blockIdx.x * 256 + threadIdx.x;
    int n = gt >> 2, p = gt & 3;
    if (n >= N) return;
    int b = rowptr[n], en = rowptr[n + 1];
    float a = 0.f;
    for (int e = b + p; e < en; e += 4) {
        int2 sw = csr[e];
        a = fmaf(__int_as_float(sw.y), x[sw.x], a);
    }
    a += __shfl_xor(a, 1);
    a += __shfl_xor(a, 2);
    if (p == 0) axn[n] = make_float2(a, x[n]);
}

// ---- layer 2 aggregation: wave per node, lane = channel --------------------
// Lane i loads edge b+i's {csr, axn} (2 VMEM instrs for up to 64 edges),
// then broadcast lane i's values via v_readlane (no memory in inner loop).
__global__ __launch_bounds__(256) void k_agg2(const int2* __restrict__ csr,
                                              const int* __restrict__ rowptr,
                                              const float2* __restrict__ axn,
                                              const float* __restrict__ W1_rel,
                                              const float* __restrict__ b1,
                                              const float* __restrict__ W1_root,
                                              float* __restrict__ agg2, int N)
{
    int n = (blockIdx.x * 256 + threadIdx.x) >> 6;
    int lane = threadIdx.x & 63;
    if (n >= N) return;
    float wrel = W1_rel[lane], wroot = W1_root[lane], bj = b1[lane];
    int b = rowptr[n], en = rowptr[n + 1];
    float acc = 0.f;

    for (int base = b; base < en; base += 64) {
        int e = base + lane;
        float wv = 0.f;
        float2 ax = make_float2(0.f, 0.f);
        if (e < en) {
            int2 sw = csr[e];            // coalesced 8B/lane
            wv = __int_as_float(sw.y);
            ax = axn[sw.x];              // per-lane gather, L2/L3-resident
        }
        int cnt = min(en - base, 64);
        int i = 0;
        for (; i + 4 <= cnt; i += 4) {
#pragma unroll
            for (int u = 0; u < 4; ++u) {
                float wi = rdlane(wv, i + u);
                float ai = rdlane(ax.x, i + u);
                float xi = rdlane(ax.y, i + u);
                float h = fmaxf(fmaf(ai, wrel, fmaf(xi, wroot, bj)), 0.f);
                acc = fmaf(wi, h, acc);
            }
        }
        for (; i < cnt; ++i) {
            float wi = rdlane(wv, i);
            float ai = rdlane(ax.x, i);
            float xi = rdlane(ax.y, i);
            float h = fmaxf(fmaf(ai, wrel, fmaf(xi, wroot, bj)), 0.f);
            acc = fmaf(wi, h, acc);
        }
    }
    agg2[(size_t)n * 64 + lane] = acc;
}

// ---- layer-2 node GEMM + layer-3 fold (round-5 structure, unchanged) -------
__global__ __launch_bounds__(256) void k_node2(const float* __restrict__ agg2,
                                               const float2* __restrict__ axn,
                                               const float* __restrict__ W2_rel,
                                               const float* __restrict__ W2_root,
                                               const float* __restrict__ b2,
                                               const float* __restrict__ W1_rel,
                                               const float* __restrict__ b1,
                                               const float* __restrict__ W1_root,
                                               const float* __restrict__ MCf,   // [64][4]
                                               float2* __restrict__ z01,
                                               float2* __restrict__ z23, int N)
{
    __shared__ float As[128 * 65];

    const int t = threadIdx.x;
    const int n0 = blockIdx.x * 128;

#pragma unroll
    for (int it = 0; it < 8; ++it) {
        int idx = it * 256 + t;
        int nl = idx >> 4, q4 = (idx & 15) << 2;
        int n = n0 + nl;
        float4 a = (n < N) ? ld4(&agg2[(size_t)n * 64 + q4])
                           : make_float4(0.f, 0.f, 0.f, 0.f);
        float* row = &As[nl * 65 + q4];
        row[0] = a.x; row[1] = a.y; row[2] = a.z; row[3] = a.w;
    }
    __syncthreads();

    const int lane = t & 63;
    const int g = (t >> 7) & 1;
    const int hs = __builtin_amdgcn_readfirstlane((t >> 6) & 1);
    const int nl = g * 64 + lane;
    const int n = n0 + nl;
    float2 ax = (n < N) ? axn[n] : make_float2(0.f, 0.f);

    float4 acc[8];
#pragma unroll
    for (int q = 0; q < 8; ++q) acc[q] = make_float4(0.f, 0.f, 0.f, 0.f);

    const float* Asr = &As[nl * 65];

    for (int c = 0; c < 8; ++c) {
        float a_[8];
#pragma unroll
        for (int i = 0; i < 8; ++i) a_[i] = Asr[c * 8 + i];
#pragma unroll
        for (int i = 0; i < 8; ++i) {
            const float* wr = &W2_rel[(size_t)(c * 8 + i) * 64 + hs * 32];
#pragma unroll
            for (int q = 0; q < 8; ++q) {
                float4 w = ld4(wr + q * 4);
                acc[q].x = fmaf(a_[i], w.x, acc[q].x);
                acc[q].y = fmaf(a_[i], w.y, acc[q].y);
                acc[q].z = fmaf(a_[i], w.z, acc[q].z);
                acc[q].w = fmaf(a_[i], w.w, acc[q].w);
            }
        }
    }

    for (int c = 0; c < 8; ++c) {
        int k0 = c * 8;
        float4 w1ra = ld4(&W1_rel[k0]),  w1rb = ld4(&W1_rel[k0 + 4]);
        float4 w1oa = ld4(&W1_root[k0]), w1ob = ld4(&W1_root[k0 + 4]);
        float4 b1a  = ld4(&b1[k0]),      b1b  = ld4(&b1[k0 + 4]);
        float hk[8];
        hk[0] = fmaxf(fmaf(ax.x, w1ra.x, fmaf(ax.y, w1oa.x, b1a.x)), 0.f);
        hk[1] = fmaxf(fmaf(ax.x, w1ra.y, fmaf(ax.y, w1oa.y, b1a.y)), 0.f);
        hk[2] = fmaxf(fmaf(ax.x, w1ra.z, fmaf(ax.y, w1oa.z, b1a.z)), 0.f);
        hk[3] = fmaxf(fmaf(ax.x, w1ra.w, fmaf(ax.y, w1oa.w, b1a.w)), 0.f);
        hk[4] = fmaxf(fmaf(ax.x, w1rb.x, fmaf(ax.y, w1ob.x, b1b.x)), 0.f);
        hk[5] = fmaxf(fmaf(ax.x, w1rb.y, fmaf(ax.y, w1ob.y, b1b.y)), 0.f);
        hk[6] = fmaxf(fmaf(ax.x, w1rb.z, fmaf(ax.y, w1ob.z, b1b.z)), 0.f);
        hk[7] = fmaxf(fmaf(ax.x, w1rb.w, fmaf(ax.y, w1ob.w, b1b.w)), 0.f);
#pragma unroll
        for (int i = 0; i < 8; ++i) {
            const float* wo = &W2_root[(size_t)(k0 + i) * 64 + hs * 32];
#pragma unroll
            for (int q = 0; q < 8; ++q) {
                float4 w = ld4(wo + q * 4);
                acc[q].x = fmaf(hk[i], w.x, acc[q].x);
                acc[q].y = fmaf(hk[i], w.y, acc[q].y);
                acc[q].z = fmaf(hk[i], w.z, acc[q].z);
                acc[q].w = fmaf(hk[i], w.w, acc[q].w);
            }
        }
    }

    float z0 = 0.f, z1 = 0.f, z2 = 0.f, z3 = 0.f;
    const float* b2h = &b2[hs * 32];
#pragma unroll
    for (int q = 0; q < 8; ++q) {
        float4 bq = ld4(b2h + q * 4);
        int jb = hs * 32 + q * 4;
        float h2;
        h2 = fmaxf(acc[q].x + bq.x, 0.f);
        { const float* m = &MCf[(jb + 0) * 4];
          z0 = fmaf(h2, m[0], z0); z1 = fmaf(h2, m[1], z1);
          z2 = fmaf(h2, m[2], z2); z3 = fmaf(h2, m[3], z3); }
        h2 = fmaxf(acc[q].y + bq.y, 0.f);
        { const float* m = &MCf[(jb + 1) * 4];
          z0 = fmaf(h2, m[0], z0); z1 = fmaf(h2, m[1], z1);
          z2 = fmaf(h2, m[2], z2); z3 = fmaf(h2, m[3], z3); }
        h2 = fmaxf(acc[q].z + bq.z, 0.f);
        { const float* m = &MCf[(jb + 2) * 4];
          z0 = fmaf(h2, m[0], z0); z1 = fmaf(h2, m[1], z1);
          z2 = fmaf(h2, m[2], z2); z3 = fmaf(h2, m[3], z3); }
        h2 = fmaxf(acc[q].w + bq.w, 0.f);
        { const float* m = &MCf[(jb + 3) * 4];
          z0 = fmaf(h2, m[0], z0); z1 = fmaf(h2, m[1], z1);
          z2 = fmaf(h2, m[2], z2); z3 = fmaf(h2, m[3], z3); }
    }

    __syncthreads();
    float* zs = As;
    *reinterpret_cast<float4*>(&zs[(nl * 2 + hs) * 4]) = make_float4(z0, z1, z2, z3);
    __syncthreads();
    if (hs == 0 && n < N) {
        float4 p0 = *reinterpret_cast<float4*>(&zs[(nl * 2 + 0) * 4]);
        float4 p1 = *reinterpret_cast<float4*>(&zs[(nl * 2 + 1) * 4]);
        z01[n] = make_float2(p0.x + p1.x, p0.y + p1.y);
        z23[n] = make_float2(p0.z + p1.z, p0.w + p1.w);
    }
}

// ---- pool: 4 threads per node, strided edges, shfl_xor combine -------------
__global__ __launch_bounds__(256) void k_pool(const int2* __restrict__ csr,
                                              const int* __restrict__ rowptr,
                                              const int* __restrict__ batch,
                                              const float2* __restrict__ z01,
                                              const float2* __restrict__ z23,
                                              float* __restrict__ gacc, int N, int G)
{
    extern __shared__ float lds[];  // [G][5]
    for (int i = threadIdx.x; i < 5 * G; i += 256) lds[i] = 0.f;
    __syncthreads();

    int gt = blockIdx.x * 256 + threadIdx.x;
    int n = gt >> 2, p = gt & 3;
    if (n < N) {
        int b = rowptr[n], en = rowptr[n + 1];
        float s0 = 0.f, s1 = 0.f;
        for (int e = b + p; e < en; e += 4) {
            int2 sw = csr[e];
            float w = __int_as_float(sw.y);
            float2 zz = z01[sw.x];
            s0 = fmaf(w, zz.x, s0);
            s1 = fmaf(w, zz.y, s1);
        }
        s0 += __shfl_xor(s0, 1);
        s0 += __shfl_xor(s0, 2);
        s1 += __shfl_xor(s1, 1);
        s1 += __shfl_xor(s1, 2);
        if (p == 0) {
            int bg = batch[n];
            float2 zw = z23[n];
            atomicAdd(&lds[bg * 5 + 0], s0);
            atomicAdd(&lds[bg * 5 + 1], s1);
            atomicAdd(&lds[bg * 5 + 2], zw.x);
            atomicAdd(&lds[bg * 5 + 3], zw.y);
            atomicAdd(&lds[bg * 5 + 4], 1.0f);
        }
    }
    __syncthreads();
    for (int i = threadIdx.x; i < 5 * G; i += 256) {
        float v = lds[i];
        if (v != 0.f) atomicAdd(&gacc[i], v);
    }
}

__global__ void k_final(const float* __restrict__ gacc, const float* __restrict__ b3W,
                        const float* __restrict__ b_lin, float* __restrict__ out, int G)
{
    int t = blockIdx.x * blockDim.x + threadIdx.x;
    if (t < G * 2) {
        int g = t >> 1, c = t & 1;
        float cnt = gacc[g * 5 + 4];
        float s = gacc[g * 5 + c] + gacc[g * 5 + 2 + c] + cnt * b3W[c];
        out[t] = s / fmaxf(cnt, 1.f) + b_lin[c];
    }
}

extern "C" void kernel_launch(void* const* d_in, const int* in_sizes, int n_in,
                              void* d_out, int out_size, void* d_ws, size_t ws_size,
                              hipStream_t stream)
{
    const float* x       = (const float*)d_in[0];
    const int*   ei      = (const int*)  d_in[1];
    const int*   batch   = (const int*)  d_in[2];
    const float* ew      = (const float*)d_in[3];
    const float* W1_rel  = (const float*)d_in[4];
    const float* b1      = (const float*)d_in[5];
    const float* W1_root = (const float*)d_in[6];
    const float* W2_rel  = (const float*)d_in[7];
    const float* b2      = (const float*)d_in[8];
    const float* W2_root = (const float*)d_in[9];
    const float* W3_rel  = (const float*)d_in[10];
    const float* b3      = (const float*)d_in[11];
    const float* W3_root = (const float*)d_in[12];
    const float* W_lin   = (const float*)d_in[13];
    const float* b_lin   = (const float*)d_in[14];
    float* out = (float*)d_out;

    const int N = in_sizes[0];
    const int E = in_sizes[3];
    const int G = out_size / 2;
    const int NB = (N + 255) / 256;
    const int* src = ei;
    const int* dst = ei + E;

    char* wsb = (char*)d_ws;
    size_t o = 0;
    auto take = [&](size_t bytes) -> char* {
        char* p = wsb + o;
        o += (bytes + 15) & ~(size_t)15;
        return p;
    };
    int*    deg    = (int*)   take((size_t)N * 4);
    int*    cursor = (int*)   take((size_t)N * 4);
    float*  gacc   = (float*) take((size_t)G * 5 * 4);
    size_t  zero_bytes = o;
    int*    rowptr = (int*)   take((size_t)(N + 1) * 4);
    int*    bsum   = (int*)   take((size_t)NB * 4);
    int*    bpref  = (int*)   take((size_t)NB * 4);
    int2*   csr    = (int2*)  take((size_t)E * 8);
    float2* axn    = (float2*)take((size_t)N * 8);
    float*  agg2   = (float*) take((size_t)N * 64 * 4);
    float2* z01    = (float2*)take((size_t)N * 8);
    float2* z23    = (float2*)take((size_t)N * 8);
    float4* MC4    = (float4*)take(64 * 16);
    float*  b3W    = (float*) take(4 * 4);

    hipMemsetAsync(d_ws, 0, zero_bytes, stream);

    hipLaunchKernelGGL(k_small, dim3(1), dim3(256), 0, stream,
                       W3_rel, b3, W3_root, W_lin, MC4, b3W);

    hipLaunchKernelGGL(k_hist, dim3((E + 255) / 256), dim3(256), 0, stream, dst, deg, E);
    hipLaunchKernelGGL(k_blocksum, dim3(NB), dim3(256), 0, stream, deg, bsum, N);
    hipLaunchKernelGGL(k_scanbsum, dim3(1), dim3(256), 0, stream, bsum, bpref, NB);
    hipLaunchKernelGGL(k_scan3, dim3(NB), dim3(256), 0, stream, deg, bpref, rowptr, N, E);
    hipLaunchKernelGGL(k_scatter, dim3((E + 255) / 256), dim3(256), 0, stream,
                       src, dst, ew, rowptr, cursor, csr, E);

    hipLaunchKernelGGL(k_agg1, dim3(((size_t)N * 4 + 255) / 256), dim3(256), 0, stream,
                       csr, rowptr, x, axn, N);

    hipLaunchKernelGGL(k_agg2, dim3((N * 64 + 255) / 256), dim3(256), 0, stream,
                       csr, rowptr, axn, W1_rel, b1, W1_root, agg2, N);

    hipLaunchKernelGGL(k_node2, dim3((N + 127) / 128), dim3(256), 0, stream,
                       agg2, axn, W2_rel, W2_root, b2, W1_rel, b1, W1_root,
                       (const float*)MC4, z01, z23, N);

    hipLaunchKernelGGL(k_pool, dim3(((size_t)N * 4 + 255) / 256), dim3(256),
                       5 * G * sizeof(float), stream,
                       csr, rowptr, batch, z01, z23, gacc, N, G);

    hipLaunchKernelGGL(k_final, dim3((G * 2 + 255) / 256), dim3(256), 0, stream,
                       gacc, b3W, b_lin, out, G);
}